// Round 1
// baseline (124.763 us; speedup 1.0000x reference)
//
#include <hip/hip_runtime.h>

// DotProductAttention: B=4 H=8 S=2048 D=16, fp32 in/out.
// out = softmax(mask ? -1e10 : 10*tanh(SCALE*(Q K^T))) V
//
// Design:
//  - logits capped at +-10 by tanh -> p = exp(logit - 10) in [e^-20, 1]:
//    no online max needed. Masked keys -> p = 0 via multiply.
//  - identity: exp(10*tanh(SCALE*s) - 10) = exp(-20 / (1 + e^{2*SCALE*s}))
//    => t = exp2(c1*s); w = rcp(1+t); p = exp2(c2*w). 3 trans ops/elem.
//  - S^T = K*Q^T via mfma_f32_16x16x16f16 (reduction dim = D = 16, no pad).
//    C-layout of S^T (col=q=lane&15, row=key=quad*4+reg) == A-layout needed
//    for P*V (m=q=lane&15, k=key=quad*4+j)  -> no shuffle between MFMAs.
//  - One WG = 4 waves x 16 q-rows = 64 q. 32 bh * 32 qblk = 1024 WGs.
//    K/V/mask staged per 256-key chunk into LDS as f16 (V transposed).

typedef _Float16 h4 __attribute__((ext_vector_type(4)));
typedef float f4 __attribute__((ext_vector_type(4)));

#define KROW 20   // f16 units per K row in LDS (40B stride, breaks bank conflicts)
#define VROW 260  // f16 units per Vt row in LDS (520B stride)

__device__ __forceinline__ float fast_exp2(float x) {
#if __has_builtin(__builtin_amdgcn_exp2f)
    return __builtin_amdgcn_exp2f(x);
#else
    return exp2f(x);
#endif
}

__global__ __launch_bounds__(256) void attn_fwd(
    const float* __restrict__ Qp, const float* __restrict__ Kp,
    const float* __restrict__ Vp, const int* __restrict__ maskp,
    float* __restrict__ out)
{
    __shared__ __align__(16) _Float16 Klds[256 * KROW]; // 10240 B
    __shared__ __align__(16) _Float16 Vt[16 * VROW];    //  8320 B
    __shared__ __align__(16) float maskf[256];          //  1024 B

    const int bid  = blockIdx.x;
    const int bh   = bid >> 5;   // 32 q-blocks per (b,h)
    const int qblk = bid & 31;
    const int b    = bh >> 3;    // H = 8
    const int tid  = threadIdx.x;
    const int wave = tid >> 6;
    const int lane = tid & 63;
    const int c    = lane & 15;  // column index within fragments
    const int g    = lane >> 4;  // quad

    const size_t base = (size_t)bh * (2048 * 16);
    const int qbase = qblk * 64 + wave * 16;

    // Q fragment = B operand of S^T mfma: lane holds Q[qbase+c][4g..4g+3] (f16)
    h4 qfrag;
    {
        f4 qv = *(const f4*)(Qp + base + (size_t)(qbase + c) * 16 + 4 * g);
        auto lo = __builtin_amdgcn_cvt_pkrtz(qv[0], qv[1]);
        auto hi = __builtin_amdgcn_cvt_pkrtz(qv[2], qv[3]);
        qfrag[0] = lo[0]; qfrag[1] = lo[1]; qfrag[2] = hi[0]; qfrag[3] = hi[1];
    }

    f4 acc = {0.f, 0.f, 0.f, 0.f};  // out rows q=qbase+4g+r, col d=c (fp32)
    float dsum = 0.f;               // partial softmax denom for q=qbase+c

    const float c1 = 1.1047809f;    // 2*SCALE*log2(e), SCALE=log(400)/log(50)/4
    const float c2 = -28.8539008f;  // -20*log2(e)

    for (int chunk = 0; chunk < 8; ++chunk) {
        // ---- stage 256 keys: K row-major f16, V transposed f16, mask mult ----
        {
            const float* Kc = Kp + base + (size_t)chunk * 256 * 16;
            const float* Vc = Vp + base + (size_t)chunk * 256 * 16;
            #pragma unroll
            for (int j = 0; j < 4; ++j) {
                f4 kv = *(const f4*)(Kc + j * 1024 + tid * 4); // coalesced 16B/lane
                f4 vv = *(const f4*)(Vc + j * 1024 + tid * 4);
                const int key = j * 64 + (tid >> 2);
                const int dq  = (tid & 3) * 4;
                auto pk0 = __builtin_amdgcn_cvt_pkrtz(kv[0], kv[1]);
                auto pk1 = __builtin_amdgcn_cvt_pkrtz(kv[2], kv[3]);
                *(decltype(pk0)*)&Klds[key * KROW + dq + 0] = pk0;
                *(decltype(pk1)*)&Klds[key * KROW + dq + 2] = pk1;
                #pragma unroll
                for (int e = 0; e < 4; ++e)
                    Vt[(dq + e) * VROW + key] = (_Float16)vv[e];
            }
            maskf[tid] = maskp[(size_t)b * 2048 + chunk * 256 + tid] ? 0.0f : 1.0f;
        }
        __syncthreads();

        // ---- 16 key-tiles of 16 ----
        for (int t = 0; t < 16; ++t) {
            const int kb = t * 16;
            // A = K tile: lane holds K[kb+c][4g..4g+3]
            h4 afrag = *(const h4*)&Klds[(kb + c) * KROW + 4 * g];
            // S^T[key=4g+r][q=c] = sum_d K[key][d] * Q[q][d]
            f4 s = __builtin_amdgcn_mfma_f32_16x16x16f16(
                afrag, qfrag, (f4){0.f, 0.f, 0.f, 0.f}, 0, 0, 0);

            f4 m4 = *(const f4*)&maskf[kb + 4 * g];  // broadcast within quad
            float p[4];
            #pragma unroll
            for (int r = 0; r < 4; ++r) {
                float tt = fast_exp2(c1 * s[r]);
                float w  = __builtin_amdgcn_rcpf(1.0f + tt);
                p[r] = fast_exp2(c2 * w) * m4[r];
            }
            dsum += (p[0] + p[1]) + (p[2] + p[3]);

            auto plo = __builtin_amdgcn_cvt_pkrtz(p[0], p[1]);
            auto phi = __builtin_amdgcn_cvt_pkrtz(p[2], p[3]);
            h4 pf; pf[0] = plo[0]; pf[1] = plo[1]; pf[2] = phi[0]; pf[3] = phi[1];

            // B = V^T tile: lane holds V[kb+4g+j][d=c]
            h4 vfrag = *(const h4*)&Vt[c * VROW + kb + 4 * g];
            acc = __builtin_amdgcn_mfma_f32_16x16x16f16(pf, vfrag, acc, 0, 0, 0);
        }
        __syncthreads();
    }

    // full denom for q=qbase+c on every lane
    dsum += __shfl_xor(dsum, 16);
    dsum += __shfl_xor(dsum, 32);

    #pragma unroll
    for (int r = 0; r < 4; ++r) {
        float denom = __shfl(dsum, 4 * g + r);  // lane 4g+r holds denom(q=4g+r)
        out[base + (size_t)(qbase + 4 * g + r) * 16 + c] = acc[r] / denom;
    }
}

extern "C" void kernel_launch(void* const* d_in, const int* in_sizes, int n_in,
                              void* d_out, int out_size, void* d_ws, size_t ws_size,
                              hipStream_t stream) {
    const float* Q    = (const float*)d_in[0];
    const float* K    = (const float*)d_in[1];
    const float* V    = (const float*)d_in[2];
    const int*   mask = (const int*)d_in[3];
    float* out = (float*)d_out;
    attn_fwd<<<dim3(1024), dim3(256), 0, stream>>>(Q, K, V, mask, out);
}

// Round 3
// 110.694 us; speedup vs baseline: 1.1271x; 1.1271x over previous
//
#include <hip/hip_runtime.h>

// DotProductAttention: B=4 H=8 S=2048 D=16, fp32 in/out.
// out = softmax(mask ? -1e10 : 10*tanh(SCALE*(Q K^T))) V
//
// Round 3 = Round 2 design with the __fp16/_Float16 type fix:
//  - p = exp(10*tanh(z)-10) = exp(-20/(1+e^{2z})): t=exp2(y); w=rcp(1+t);
//    p=exp2(fma(c2,w,maskbias)).  3 trans + 2 VALU per element.
//  - Q pre-scaled by c1=2*SCALE*log2(e) before f16 pack -> s comes out of the
//    MFMA already in exp2 domain.
//  - mask folded as additive bias (-60 => p<=2^-60, negligible vs min
//    unmasked p=2^-28.85) inside the fma.
//  - denominator via v_dot2_f32_f16 on the already-packed p.
//  - S^T = K*Q^T via mfma_f32_16x16x16f16; its C-layout == A-layout of P for
//    the PV MFMA -> no shuffle between the two MFMAs.
//  - WG = 512 threads = 8 waves = 4 q-tiles x 2 key-groups. 1024 WGs ->
//    8192 waves = 32/CU (100% of slots; LDS 39KB -> 4 blocks/CU fits 160KB).
//    Key-groups combine partial (O, denom) through LDS at the end.
//  - staging: 4 rounds of 512 keys; K written as single 8B LDS stores.
//
// NOTE: h2/h4 are __fp16 vectors — clang's amdgcn builtins (cvt_pkrtz, fdot2,
// mfma_*f16) are typed on __fp16 vectors; _Float16 vectors fail to convert.

typedef __fp16 h2 __attribute__((ext_vector_type(2)));
typedef __fp16 h4 __attribute__((ext_vector_type(4)));
typedef float  f4 __attribute__((ext_vector_type(4)));

#define KROW 20   // f16 per K row in LDS (40B stride)
#define VROW 520  // f16 per Vt row in LDS (1040B stride)

__device__ __forceinline__ float fast_exp2(float x) {
#if __has_builtin(__builtin_amdgcn_exp2f)
    return __builtin_amdgcn_exp2f(x);
#else
    return exp2f(x);
#endif
}

__device__ __forceinline__ float dot2acc(h2 a, float accv) {
#if __has_builtin(__builtin_amdgcn_fdot2)
    const h2 one = {(__fp16)1.0f, (__fp16)1.0f};
    return __builtin_amdgcn_fdot2(a, one, accv, false);
#else
    return accv + (float)a[0] + (float)a[1];
#endif
}

__global__ __launch_bounds__(512, 8) void attn_fwd(
    const float* __restrict__ Qp, const float* __restrict__ Kp,
    const float* __restrict__ Vp, const int* __restrict__ maskp,
    float* __restrict__ out)
{
    __shared__ __align__(16) _Float16 Klds[512 * KROW]; // 20480 B
    __shared__ __align__(16) _Float16 Vt[16 * VROW];    // 16640 B
    __shared__ __align__(16) float biasf[512];          //  2048 B

    const int bid  = blockIdx.x;
    const int bh   = bid >> 5;   // 32 q-blocks per (b,h)
    const int qblk = bid & 31;
    const int b    = bh >> 3;    // H = 8
    const int tid  = threadIdx.x;
    const int wave = tid >> 6;
    const int lane = tid & 63;
    const int qt   = wave & 3;   // q-tile within the WG's 64 q
    const int kg   = wave >> 2;  // key-group: 0 -> first 256 of each 512, 1 -> second
    const int c    = lane & 15;
    const int g    = lane >> 4;

    const size_t base = (size_t)bh * (2048 * 16);
    const int qbase = qblk * 64 + qt * 16;

    const float c1 = 1.1047809f;    // 2*SCALE*log2(e)
    const float c2 = -28.8539008f;  // -20*log2(e)

    // Q fragment (B operand): lane holds c1*Q[qbase+c][4g..4g+3] as f16
    h4 qfrag;
    {
        f4 qv = *(const f4*)(Qp + base + (size_t)(qbase + c) * 16 + 4 * g);
        h2 lo = __builtin_amdgcn_cvt_pkrtz(c1 * qv[0], c1 * qv[1]);
        h2 hi = __builtin_amdgcn_cvt_pkrtz(c1 * qv[2], c1 * qv[3]);
        qfrag[0] = lo[0]; qfrag[1] = lo[1]; qfrag[2] = hi[0]; qfrag[3] = hi[1];
    }

    f4 acc = {0.f, 0.f, 0.f, 0.f};  // partial out rows q=qbase+4g+r, col d=c
    float dsum = 0.f;               // partial denom for q=qbase+c

    const int kgb = kg * 256;

    for (int round = 0; round < 4; ++round) {
        // ---- stage 512 keys: K row-major f16, V transposed f16, mask bias ----
        {
            const float* Kc = Kp + base + (size_t)round * (512 * 16);
            const float* Vc = Vp + base + (size_t)round * (512 * 16);
            #pragma unroll
            for (int j = 0; j < 4; ++j) {
                const int i = j * 512 + tid;        // f4 index, coalesced
                f4 kv = *(const f4*)(Kc + (size_t)i * 4);
                f4 vv = *(const f4*)(Vc + (size_t)i * 4);
                const int key = i >> 2;             // 0..511
                const int dq  = (i & 3) * 4;
                h2 k0 = __builtin_amdgcn_cvt_pkrtz(kv[0], kv[1]);
                h2 k1 = __builtin_amdgcn_cvt_pkrtz(kv[2], kv[3]);
                h4 kh; kh[0] = k0[0]; kh[1] = k0[1]; kh[2] = k1[0]; kh[3] = k1[1];
                *(h4*)&Klds[key * KROW + dq] = kh;  // single 8B store
                #pragma unroll
                for (int e = 0; e < 4; ++e)
                    Vt[(dq + e) * VROW + key] = (_Float16)vv[e];
            }
            biasf[tid] = maskp[(size_t)b * 2048 + round * 512 + tid] ? -60.0f : 0.0f;
        }
        __syncthreads();

        // ---- this wave's 16 key-tiles of 16 ----
        #pragma unroll
        for (int t = 0; t < 16; ++t) {
            const int kb = kgb + t * 16;
            h4 afrag = *(const h4*)&Klds[(kb + c) * KROW + 4 * g];
            f4 s = __builtin_amdgcn_mfma_f32_16x16x16f16(
                afrag, qfrag, (f4){0.f, 0.f, 0.f, 0.f}, 0, 0, 0);

            f4 b4 = *(const f4*)&biasf[kb + 4 * g];
            float p[4];
            #pragma unroll
            for (int r = 0; r < 4; ++r) {
                float tt = fast_exp2(s[r]);
                float w  = __builtin_amdgcn_rcpf(1.0f + tt);
                p[r] = fast_exp2(__builtin_fmaf(c2, w, b4[r]));
            }
            h2 plo = __builtin_amdgcn_cvt_pkrtz(p[0], p[1]);
            h2 phi = __builtin_amdgcn_cvt_pkrtz(p[2], p[3]);
            dsum = dot2acc(plo, dsum);
            dsum = dot2acc(phi, dsum);
            h4 pf; pf[0] = plo[0]; pf[1] = plo[1]; pf[2] = phi[0]; pf[3] = phi[1];

            h4 vfrag = *(const h4*)&Vt[c * VROW + kb + 4 * g];
            acc = __builtin_amdgcn_mfma_f32_16x16x16f16(pf, vfrag, acc, 0, 0, 0);
        }
        __syncthreads();
    }

    // within-wave: full denom over this key-group for q=qbase+c, on all lanes
    dsum += __shfl_xor(dsum, 16);
    dsum += __shfl_xor(dsum, 32);

    // cross-key-group combine through LDS (reuse Klds; safe after the loop's
    // trailing __syncthreads)
    float* ex = (float*)Klds;
    const int slot = (qt * 64 + lane) * 5;
    if (kg == 1) {
        ex[slot + 0] = acc[0]; ex[slot + 1] = acc[1];
        ex[slot + 2] = acc[2]; ex[slot + 3] = acc[3];
        ex[slot + 4] = dsum;
    }
    __syncthreads();
    if (kg == 0) {
        const float dT = dsum + ex[slot + 4];
        #pragma unroll
        for (int r = 0; r < 4; ++r) {
            const float denom = __shfl(dT, 4 * g + r); // lane 4g+r holds q=4g+r denom
            out[base + (size_t)(qbase + 4 * g + r) * 16 + c] =
                (acc[r] + ex[slot + r]) / denom;
        }
    }
}

extern "C" void kernel_launch(void* const* d_in, const int* in_sizes, int n_in,
                              void* d_out, int out_size, void* d_ws, size_t ws_size,
                              hipStream_t stream) {
    const float* Q    = (const float*)d_in[0];
    const float* K    = (const float*)d_in[1];
    const float* V    = (const float*)d_in[2];
    const int*   mask = (const int*)d_in[3];
    float* out = (float*)d_out;
    attn_fwd<<<dim3(1024), dim3(512), 0, stream>>>(Q, K, V, mask, out);
}

// Round 4
// 106.633 us; speedup vs baseline: 1.1700x; 1.0381x over previous
//
#include <hip/hip_runtime.h>

// DotProductAttention: B=4 H=8 S=2048 D=16, fp32 in/out.
// out = softmax(mask ? -1e10 : 10*tanh(SCALE*(Q K^T))) V
//
// Round 4:
//  * prep kernel writes K,V as MFMA-fragment-major f16 into d_ws
//    (tile = 16 keys -> 64 lanes x 8B, lane order == hot-loop read order),
//    plus bias[b][key] = mask ? -60 : 0.
//  * hot kernel: staging = contiguous 16B/thread f4 copies ws->LDS
//    (conflict-free b128 writes / b64 reads), double-buffered LDS
//    (2 x (8KB K + 8KB V + 1KB bias) = 34KB -> 4 blocks/CU), register
//    prefetch 2 rounds ahead, ONE barrier per 256-key round.
//  - math unchanged vs round 3: p = exp2(fma(c2, rcp(1+exp2(s)), bias)),
//    Q pre-scaled by c1; denominator via v_dot2_f32_f16 on packed p.
//  - fallback: if ws_size too small, run the round-3 kernel.

typedef __fp16 h2 __attribute__((ext_vector_type(2)));
typedef __fp16 h4 __attribute__((ext_vector_type(4)));
typedef float  f4 __attribute__((ext_vector_type(4)));

#define SEQ 2048
#define NBH 32
#define TPB 128  // tiles (of 16 keys) per bh
#define KWS_BYTES ((size_t)NBH * TPB * 64 * 8)   // 2 MB
#define VWS_BYTES KWS_BYTES                      // 2 MB
#define BIAS_BYTES ((size_t)4 * SEQ * 4)         // 32 KB
#define WS_NEEDED (KWS_BYTES + VWS_BYTES + BIAS_BYTES)

__device__ __forceinline__ float fast_exp2(float x) {
#if __has_builtin(__builtin_amdgcn_exp2f)
    return __builtin_amdgcn_exp2f(x);
#else
    return exp2f(x);
#endif
}

__device__ __forceinline__ float dot2acc(h2 a, float accv) {
#if __has_builtin(__builtin_amdgcn_fdot2)
    const h2 one = {(__fp16)1.0f, (__fp16)1.0f};
    return __builtin_amdgcn_fdot2(a, one, accv, false);
#else
    return accv + (float)a[0] + (float)a[1];
#endif
}

// ---------------- prep: K,V -> fragment-major f16 in ws; mask -> bias ----------------
__global__ __launch_bounds__(256) void attn_prep(
    const float* __restrict__ Kp, const float* __restrict__ Vp,
    const int* __restrict__ maskp,
    __fp16* __restrict__ Kws, __fp16* __restrict__ Vws, float* __restrict__ biasws)
{
    const int tid = threadIdx.x;
    const int T   = blockIdx.x * 4 + (tid >> 6);  // global tile 0..4095
    const int l   = tid & 63;
    const int bh  = T >> 7;
    const int t   = T & (TPB - 1);
    const int c   = l & 15;
    const int g   = l >> 4;
    const size_t base = (size_t)bh * (SEQ * 16);

    // K fragment (A operand of S^T mfma): lane l holds K[t*16+c][4g..4g+3]
    {
        f4 kv = *(const f4*)(Kp + base + (size_t)(t * 16 + c) * 16 + 4 * g);
        h2 k0 = __builtin_amdgcn_cvt_pkrtz(kv[0], kv[1]);
        h2 k1 = __builtin_amdgcn_cvt_pkrtz(kv[2], kv[3]);
        h4 kh; kh[0] = k0[0]; kh[1] = k0[1]; kh[2] = k1[0]; kh[3] = k1[1];
        *(h4*)(Kws + ((size_t)T * 64 + l) * 4) = kh;
    }
    // V fragment (B operand of PV mfma): lane l holds V[t*16+4g+j][c], j=0..3
    {
        const float* vrow = Vp + base + (size_t)(t * 16 + 4 * g) * 16 + c;
        h2 p0 = __builtin_amdgcn_cvt_pkrtz(vrow[0],  vrow[16]);
        h2 p1 = __builtin_amdgcn_cvt_pkrtz(vrow[32], vrow[48]);
        h4 vh; vh[0] = p0[0]; vh[1] = p0[1]; vh[2] = p1[0]; vh[3] = p1[1];
        *(h4*)(Vws + ((size_t)T * 64 + l) * 4) = vh;
    }
    // bias: 8192 entries handled by the first 32 blocks
    if (blockIdx.x < 32) {
        const int idx = blockIdx.x * 256 + tid;  // = b*2048 + key
        biasws[idx] = maskp[idx] ? -60.0f : 0.0f;
    }
}

// ---------------- hot kernel: fragment staging + double buffer ----------------
__global__ __launch_bounds__(512, 8) void attn_v4(
    const float* __restrict__ Qp, const __fp16* __restrict__ Kws,
    const __fp16* __restrict__ Vws, const float* __restrict__ biasws,
    float* __restrict__ out)
{
    __shared__ __align__(16) _Float16 Kbuf[2][4096]; // 16 KB
    __shared__ __align__(16) _Float16 Vbuf[2][4096]; // 16 KB
    __shared__ __align__(16) float    Bbuf[2][256];  //  2 KB

    const int bid  = blockIdx.x;
    const int bh   = bid >> 5;
    const int qblk = bid & 31;
    const int b    = bh >> 3;
    const int tid  = threadIdx.x;
    const int wave = tid >> 6;
    const int lane = tid & 63;
    const int qt   = wave & 3;   // q-tile
    const int kg   = wave >> 2;  // key-group (tiles 0..7 vs 8..15 of each round)
    const int c    = lane & 15;
    const int g    = lane >> 4;

    const size_t base  = (size_t)bh * (SEQ * 16);
    const int    qbase = qblk * 64 + qt * 16;
    const float  c1 = 1.1047809f;    // 2*SCALE*log2(e)
    const float  c2 = -28.8539008f;  // -20*log2(e)

    // Q fragment (B operand): lane holds c1*Q[qbase+c][4g..4g+3]
    h4 qfrag;
    {
        f4 qv = *(const f4*)(Qp + base + (size_t)(qbase + c) * 16 + 4 * g);
        h2 lo = __builtin_amdgcn_cvt_pkrtz(c1 * qv[0], c1 * qv[1]);
        h2 hi = __builtin_amdgcn_cvt_pkrtz(c1 * qv[2], c1 * qv[3]);
        qfrag[0] = lo[0]; qfrag[1] = lo[1]; qfrag[2] = hi[0]; qfrag[3] = hi[1];
    }

    // staging sources: per round = 16 tiles * 512B = 8KB = 512 f4; thread -> one f4
    const f4* ksrc = (const f4*)(Kws + (size_t)bh * TPB * 256);
    const f4* vsrc = (const f4*)(Vws + (size_t)bh * TPB * 256);
    const float* bsrc = biasws + (size_t)b * SEQ;

    f4 kpre = ksrc[tid];
    f4 vpre = vsrc[tid];
    float bpre = (tid < 256) ? bsrc[tid] : 0.0f;
    *(f4*)&Kbuf[0][tid * 8] = kpre;
    *(f4*)&Vbuf[0][tid * 8] = vpre;
    if (tid < 256) Bbuf[0][tid] = bpre;
    kpre = ksrc[512 + tid];
    vpre = vsrc[512 + tid];
    if (tid < 256) bpre = bsrc[256 + tid];
    __syncthreads();

    f4 acc = {0.f, 0.f, 0.f, 0.f};
    float dsum = 0.f;

    for (int r = 0; r < 8; ++r) {
        const int cb = r & 1, nb = (r + 1) & 1;
        if (r < 7) {  // publish prefetched round r+1
            *(f4*)&Kbuf[nb][tid * 8] = kpre;
            *(f4*)&Vbuf[nb][tid * 8] = vpre;
            if (tid < 256) Bbuf[nb][tid] = bpre;
        }
        if (r < 6) {  // issue loads for round r+2 (a full round to land)
            kpre = ksrc[(r + 2) * 512 + tid];
            vpre = vsrc[(r + 2) * 512 + tid];
            if (tid < 256) bpre = bsrc[(r + 2) * 256 + tid];
        }

        const _Float16* Kc = &Kbuf[cb][kg * 2048];
        const _Float16* Vc = &Vbuf[cb][kg * 2048];
        const float*    Bc = &Bbuf[cb][kg * 128];

        #pragma unroll
        for (int t = 0; t < 8; ++t) {
            h4 afrag = *(const h4*)(Kc + t * 256 + lane * 4);
            f4 s = __builtin_amdgcn_mfma_f32_16x16x16f16(
                afrag, qfrag, (f4){0.f, 0.f, 0.f, 0.f}, 0, 0, 0);

            f4 b4 = *(const f4*)(Bc + t * 16 + 4 * g);
            float p[4];
            #pragma unroll
            for (int i = 0; i < 4; ++i) {
                float tt = fast_exp2(s[i]);
                float w  = __builtin_amdgcn_rcpf(1.0f + tt);
                p[i] = fast_exp2(__builtin_fmaf(c2, w, b4[i]));
            }
            h2 plo = __builtin_amdgcn_cvt_pkrtz(p[0], p[1]);
            h2 phi = __builtin_amdgcn_cvt_pkrtz(p[2], p[3]);
            dsum = dot2acc(plo, dsum);
            dsum = dot2acc(phi, dsum);
            h4 pf; pf[0] = plo[0]; pf[1] = plo[1]; pf[2] = phi[0]; pf[3] = phi[1];

            h4 vfrag = *(const h4*)(Vc + t * 256 + lane * 4);
            acc = __builtin_amdgcn_mfma_f32_16x16x16f16(pf, vfrag, acc, 0, 0, 0);
        }
        __syncthreads();
    }

    // denom over this key-group for q=qbase+c, on all lanes of the wave
    dsum += __shfl_xor(dsum, 16);
    dsum += __shfl_xor(dsum, 32);

    // cross-key-group combine through LDS (reuse Kbuf; last barrier already done)
    float* ex = (float*)&Kbuf[0][0];  // 2048 floats available, need 1280
    const int slot = (qt * 64 + lane) * 5;
    if (kg == 1) {
        ex[slot + 0] = acc[0]; ex[slot + 1] = acc[1];
        ex[slot + 2] = acc[2]; ex[slot + 3] = acc[3];
        ex[slot + 4] = dsum;
    }
    __syncthreads();
    if (kg == 0) {
        const float dT = dsum + ex[slot + 4];
        #pragma unroll
        for (int i = 0; i < 4; ++i) {
            const float denom = __shfl(dT, 4 * g + i);
            out[base + (size_t)(qbase + 4 * g + i) * 16 + c] =
                (acc[i] + ex[slot + i]) / denom;
        }
    }
}

// ---------------- round-3 fallback (ws too small) ----------------
#define KROW 20
#define VROW 520

__global__ __launch_bounds__(512, 8) void attn_fwd_v3(
    const float* __restrict__ Qp, const float* __restrict__ Kp,
    const float* __restrict__ Vp, const int* __restrict__ maskp,
    float* __restrict__ out)
{
    __shared__ __align__(16) _Float16 Klds[512 * KROW];
    __shared__ __align__(16) _Float16 Vt[16 * VROW];
    __shared__ __align__(16) float biasf[512];

    const int bid  = blockIdx.x;
    const int bh   = bid >> 5;
    const int qblk = bid & 31;
    const int b    = bh >> 3;
    const int tid  = threadIdx.x;
    const int wave = tid >> 6;
    const int lane = tid & 63;
    const int qt   = wave & 3;
    const int kg   = wave >> 2;
    const int c    = lane & 15;
    const int g    = lane >> 4;

    const size_t base = (size_t)bh * (SEQ * 16);
    const int qbase = qblk * 64 + qt * 16;
    const float c1 = 1.1047809f;
    const float c2 = -28.8539008f;

    h4 qfrag;
    {
        f4 qv = *(const f4*)(Qp + base + (size_t)(qbase + c) * 16 + 4 * g);
        h2 lo = __builtin_amdgcn_cvt_pkrtz(c1 * qv[0], c1 * qv[1]);
        h2 hi = __builtin_amdgcn_cvt_pkrtz(c1 * qv[2], c1 * qv[3]);
        qfrag[0] = lo[0]; qfrag[1] = lo[1]; qfrag[2] = hi[0]; qfrag[3] = hi[1];
    }

    f4 acc = {0.f, 0.f, 0.f, 0.f};
    float dsum = 0.f;
    const int kgb = kg * 256;

    for (int round = 0; round < 4; ++round) {
        {
            const float* Kc = Kp + base + (size_t)round * (512 * 16);
            const float* Vc = Vp + base + (size_t)round * (512 * 16);
            #pragma unroll
            for (int j = 0; j < 4; ++j) {
                const int i = j * 512 + tid;
                f4 kv = *(const f4*)(Kc + (size_t)i * 4);
                f4 vv = *(const f4*)(Vc + (size_t)i * 4);
                const int key = i >> 2;
                const int dq  = (i & 3) * 4;
                h2 k0 = __builtin_amdgcn_cvt_pkrtz(kv[0], kv[1]);
                h2 k1 = __builtin_amdgcn_cvt_pkrtz(kv[2], kv[3]);
                h4 kh; kh[0] = k0[0]; kh[1] = k0[1]; kh[2] = k1[0]; kh[3] = k1[1];
                *(h4*)&Klds[key * KROW + dq] = kh;
                #pragma unroll
                for (int e = 0; e < 4; ++e)
                    Vt[(dq + e) * VROW + key] = (_Float16)vv[e];
            }
            biasf[tid] = maskp[(size_t)b * SEQ + round * 512 + tid] ? -60.0f : 0.0f;
        }
        __syncthreads();

        #pragma unroll
        for (int t = 0; t < 16; ++t) {
            const int kb = kgb + t * 16;
            h4 afrag = *(const h4*)&Klds[(kb + c) * KROW + 4 * g];
            f4 s = __builtin_amdgcn_mfma_f32_16x16x16f16(
                afrag, qfrag, (f4){0.f, 0.f, 0.f, 0.f}, 0, 0, 0);
            f4 b4 = *(const f4*)&biasf[kb + 4 * g];
            float p[4];
            #pragma unroll
            for (int i = 0; i < 4; ++i) {
                float tt = fast_exp2(s[i]);
                float w  = __builtin_amdgcn_rcpf(1.0f + tt);
                p[i] = fast_exp2(__builtin_fmaf(c2, w, b4[i]));
            }
            h2 plo = __builtin_amdgcn_cvt_pkrtz(p[0], p[1]);
            h2 phi = __builtin_amdgcn_cvt_pkrtz(p[2], p[3]);
            dsum = dot2acc(plo, dsum);
            dsum = dot2acc(phi, dsum);
            h4 pf; pf[0] = plo[0]; pf[1] = plo[1]; pf[2] = phi[0]; pf[3] = phi[1];
            h4 vfrag = *(const h4*)&Vt[c * VROW + kb + 4 * g];
            acc = __builtin_amdgcn_mfma_f32_16x16x16f16(pf, vfrag, acc, 0, 0, 0);
        }
        __syncthreads();
    }

    dsum += __shfl_xor(dsum, 16);
    dsum += __shfl_xor(dsum, 32);

    float* ex = (float*)Klds;
    const int slot = (qt * 64 + lane) * 5;
    if (kg == 1) {
        ex[slot + 0] = acc[0]; ex[slot + 1] = acc[1];
        ex[slot + 2] = acc[2]; ex[slot + 3] = acc[3];
        ex[slot + 4] = dsum;
    }
    __syncthreads();
    if (kg == 0) {
        const float dT = dsum + ex[slot + 4];
        #pragma unroll
        for (int i = 0; i < 4; ++i) {
            const float denom = __shfl(dT, 4 * g + i);
            out[base + (size_t)(qbase + 4 * g + i) * 16 + c] =
                (acc[i] + ex[slot + i]) / denom;
        }
    }
}

extern "C" void kernel_launch(void* const* d_in, const int* in_sizes, int n_in,
                              void* d_out, int out_size, void* d_ws, size_t ws_size,
                              hipStream_t stream) {
    const float* Q    = (const float*)d_in[0];
    const float* K    = (const float*)d_in[1];
    const float* V    = (const float*)d_in[2];
    const int*   mask = (const int*)d_in[3];
    float* out = (float*)d_out;

    if (ws_size >= WS_NEEDED) {
        __fp16* Kws = (__fp16*)d_ws;
        __fp16* Vws = (__fp16*)((char*)d_ws + KWS_BYTES);
        float*  Bws = (float*)((char*)d_ws + KWS_BYTES + VWS_BYTES);
        attn_prep<<<dim3(1024), dim3(256), 0, stream>>>(K, V, mask, Kws, Vws, Bws);
        attn_v4<<<dim3(1024), dim3(512), 0, stream>>>(Q, Kws, Vws, Bws, out);
    } else {
        attn_fwd_v3<<<dim3(1024), dim3(512), 0, stream>>>(Q, K, V, mask, out);
    }
}

// Round 5
// 93.381 us; speedup vs baseline: 1.3361x; 1.1419x over previous
//
#include <hip/hip_runtime.h>

// DotProductAttention: B=4 H=8 S=2048 D=16, fp32 in/out.
// out = softmax(mask ? -1e10 : 10*tanh(SCALE*(Q K^T))) V
//
// Round 5: mask-aware key compaction. ~50% of keys are masked (randint 0/2)
// and contribute p = 0 EXACTLY (exp(-1e10-m) underflows in the fp32 reference
// too, so the denominator is unchanged). Mask is per (b,key) — shared by all
// heads & queries — so compact once per batch:
//   scan kernel  : per-batch prefix sum of ~mask -> gather idx list, count,
//                  bias (0 for real keys, -1e30 for tail pads -> p==0).
//   gather prep  : K,V gathered through idx into MFMA-fragment-major f16 ws
//                  tiles (identical layout to round 4).
//   hot kernel   : identical math, but rounds = ceil(cnt[b]/256) (~4 not 8),
//                  dynamic trip count read from device memory (graph-safe).
// Everything else (fragment staging, double buffer, 1 barrier/round,
// conflict-free b128/b64 LDS) carried from round 4.

typedef __fp16 h2 __attribute__((ext_vector_type(2)));
typedef __fp16 h4 __attribute__((ext_vector_type(4)));
typedef float  f4 __attribute__((ext_vector_type(4)));

#define SEQ 2048
#define NBH 32
#define TPB 128  // max tiles (of 16 keys) per bh
#define KWS_BYTES ((size_t)NBH * TPB * 64 * 8)   // 2 MB
#define VWS_BYTES KWS_BYTES                      // 2 MB
#define BIAS_BYTES ((size_t)4 * SEQ * 4)         // 32 KB
#define IDX_BYTES  ((size_t)4 * SEQ * 4)         // 32 KB
#define META_BYTES 64
#define WS_NEEDED (KWS_BYTES + VWS_BYTES + BIAS_BYTES + IDX_BYTES + META_BYTES)

__device__ __forceinline__ float fast_exp2(float x) {
#if __has_builtin(__builtin_amdgcn_exp2f)
    return __builtin_amdgcn_exp2f(x);
#else
    return exp2f(x);
#endif
}

__device__ __forceinline__ float dot2acc(h2 a, float accv) {
#if __has_builtin(__builtin_amdgcn_fdot2)
    const h2 one = {(__fp16)1.0f, (__fp16)1.0f};
    return __builtin_amdgcn_fdot2(a, one, accv, false);
#else
    return accv + (float)a[0] + (float)a[1];
#endif
}

// ---------------- scan: per-batch compaction of unmasked keys ----------------
__global__ __launch_bounds__(256) void attn_scan(
    const int* __restrict__ maskp, int* __restrict__ idxws,
    float* __restrict__ biasws, int* __restrict__ meta)
{
    __shared__ int partial[256];
    const int b   = blockIdx.x;
    const int tid = threadIdx.x;

    int keep[8], cnt = 0;
    #pragma unroll
    for (int j = 0; j < 8; ++j) {
        keep[j] = (maskp[b * SEQ + tid * 8 + j] == 0);
        cnt += keep[j];
    }
    partial[tid] = cnt;
    __syncthreads();
    // Hillis-Steele inclusive scan over 256 thread partials
    for (int off = 1; off < 256; off <<= 1) {
        int add = (tid >= off) ? partial[tid - off] : 0;
        __syncthreads();
        partial[tid] += add;
        __syncthreads();
    }
    const int total = partial[255];
    int pos = partial[tid] - cnt;  // exclusive prefix
    #pragma unroll
    for (int j = 0; j < 8; ++j) {
        if (keep[j]) idxws[b * SEQ + pos++] = tid * 8 + j;
    }
    for (int i = tid; i < SEQ; i += 256) {
        biasws[b * SEQ + i] = (i < total) ? 0.0f : -1.0e30f;
        if (i >= total) idxws[b * SEQ + i] = 0;  // clamp pad gathers
    }
    if (tid == 0) {
        int nr = (total + 255) >> 8;           // 256-key rounds
        meta[b] = nr < 1 ? 1 : nr;
    }
}

// ---------------- gather prep: compacted K,V -> fragment-major f16 ----------------
__global__ __launch_bounds__(256) void attn_prep(
    const float* __restrict__ Kp, const float* __restrict__ Vp,
    const int* __restrict__ idxws,
    __fp16* __restrict__ Kws, __fp16* __restrict__ Vws)
{
    const int tid = threadIdx.x;
    const int T   = blockIdx.x * 4 + (tid >> 6);  // global tile 0..4095
    const int l   = tid & 63;
    const int bh  = T >> 7;
    const int t   = T & (TPB - 1);
    const int b   = bh >> 3;
    const int c   = l & 15;
    const int g   = l >> 4;
    const size_t base = (size_t)bh * (SEQ * 16);
    const int*   idx  = idxws + (size_t)b * SEQ;

    // K fragment (A operand): lane l holds K[idx[t*16+c]][4g..4g+3]
    {
        const int krow = idx[t * 16 + c];
        f4 kv = *(const f4*)(Kp + base + (size_t)krow * 16 + 4 * g);
        h2 k0 = __builtin_amdgcn_cvt_pkrtz(kv[0], kv[1]);
        h2 k1 = __builtin_amdgcn_cvt_pkrtz(kv[2], kv[3]);
        h4 kh; kh[0] = k0[0]; kh[1] = k0[1]; kh[2] = k1[0]; kh[3] = k1[1];
        *(h4*)(Kws + ((size_t)T * 64 + l) * 4) = kh;
    }
    // V fragment (B operand): lane l holds V[idx[t*16+4g+j]][c], j=0..3
    {
        const int v0 = idx[t * 16 + 4 * g + 0];
        const int v1 = idx[t * 16 + 4 * g + 1];
        const int v2 = idx[t * 16 + 4 * g + 2];
        const int v3 = idx[t * 16 + 4 * g + 3];
        h2 p0 = __builtin_amdgcn_cvt_pkrtz(Vp[base + (size_t)v0 * 16 + c],
                                           Vp[base + (size_t)v1 * 16 + c]);
        h2 p1 = __builtin_amdgcn_cvt_pkrtz(Vp[base + (size_t)v2 * 16 + c],
                                           Vp[base + (size_t)v3 * 16 + c]);
        h4 vh; vh[0] = p0[0]; vh[1] = p0[1]; vh[2] = p1[0]; vh[3] = p1[1];
        *(h4*)(Vws + ((size_t)T * 64 + l) * 4) = vh;
    }
}

// ---------------- hot kernel: dynamic round count ----------------
__global__ __launch_bounds__(512, 8) void attn_v5(
    const float* __restrict__ Qp, const __fp16* __restrict__ Kws,
    const __fp16* __restrict__ Vws, const float* __restrict__ biasws,
    const int* __restrict__ meta, float* __restrict__ out)
{
    __shared__ __align__(16) _Float16 Kbuf[2][4096]; // 16 KB
    __shared__ __align__(16) _Float16 Vbuf[2][4096]; // 16 KB
    __shared__ __align__(16) float    Bbuf[2][256];  //  2 KB

    const int bid  = blockIdx.x;
    const int bh   = bid >> 5;
    const int qblk = bid & 31;
    const int b    = bh >> 3;
    const int tid  = threadIdx.x;
    const int wave = tid >> 6;
    const int lane = tid & 63;
    const int qt   = wave & 3;   // q-tile
    const int kg   = wave >> 2;  // key-group (tiles 0..7 vs 8..15 of a round)
    const int c    = lane & 15;
    const int g    = lane >> 4;

    const size_t base  = (size_t)bh * (SEQ * 16);
    const int    qbase = qblk * 64 + qt * 16;
    const float  c1 = 1.1047809f;    // 2*SCALE*log2(e)
    const float  c2 = -28.8539008f;  // -20*log2(e)

    const int nr = meta[b];          // rounds of 256 compacted keys (1..8)

    // Q fragment (B operand): lane holds c1*Q[qbase+c][4g..4g+3]
    h4 qfrag;
    {
        f4 qv = *(const f4*)(Qp + base + (size_t)(qbase + c) * 16 + 4 * g);
        h2 lo = __builtin_amdgcn_cvt_pkrtz(c1 * qv[0], c1 * qv[1]);
        h2 hi = __builtin_amdgcn_cvt_pkrtz(c1 * qv[2], c1 * qv[3]);
        qfrag[0] = lo[0]; qfrag[1] = lo[1]; qfrag[2] = hi[0]; qfrag[3] = hi[1];
    }

    // staging: round = 16 tiles * 512B = 8KB = 512 f4; thread -> one f4
    const f4* ksrc = (const f4*)(Kws + (size_t)bh * TPB * 256);
    const f4* vsrc = (const f4*)(Vws + (size_t)bh * TPB * 256);
    const float* bsrc = biasws + (size_t)b * SEQ;

    f4 kpre = ksrc[tid];
    f4 vpre = vsrc[tid];
    float bpre = (tid < 256) ? bsrc[tid] : 0.0f;
    *(f4*)&Kbuf[0][tid * 8] = kpre;
    *(f4*)&Vbuf[0][tid * 8] = vpre;
    if (tid < 256) Bbuf[0][tid] = bpre;
    {
        const int r1 = (1 < nr) ? 1 : (nr - 1);
        kpre = ksrc[r1 * 512 + tid];
        vpre = vsrc[r1 * 512 + tid];
        if (tid < 256) bpre = bsrc[r1 * 256 + tid];
    }
    __syncthreads();

    f4 acc = {0.f, 0.f, 0.f, 0.f};
    float dsum = 0.f;

    for (int r = 0; r < nr; ++r) {
        const int cb = r & 1, nb = cb ^ 1;
        if (r + 1 < nr) {  // publish prefetched round r+1
            *(f4*)&Kbuf[nb][tid * 8] = kpre;
            *(f4*)&Vbuf[nb][tid * 8] = vpre;
            if (tid < 256) Bbuf[nb][tid] = bpre;
        }
        if (r + 2 < nr) {  // issue loads for round r+2
            kpre = ksrc[(r + 2) * 512 + tid];
            vpre = vsrc[(r + 2) * 512 + tid];
            if (tid < 256) bpre = bsrc[(r + 2) * 256 + tid];
        }

        const _Float16* Kc = &Kbuf[cb][kg * 2048];
        const _Float16* Vc = &Vbuf[cb][kg * 2048];
        const float*    Bc = &Bbuf[cb][kg * 128];

        #pragma unroll
        for (int t = 0; t < 8; ++t) {
            h4 afrag = *(const h4*)(Kc + t * 256 + lane * 4);
            f4 s = __builtin_amdgcn_mfma_f32_16x16x16f16(
                afrag, qfrag, (f4){0.f, 0.f, 0.f, 0.f}, 0, 0, 0);

            f4 b4 = *(const f4*)(Bc + t * 16 + 4 * g);
            float p[4];
            #pragma unroll
            for (int i = 0; i < 4; ++i) {
                float tt = fast_exp2(s[i]);
                float w  = __builtin_amdgcn_rcpf(1.0f + tt);
                p[i] = fast_exp2(__builtin_fmaf(c2, w, b4[i]));
            }
            h2 plo = __builtin_amdgcn_cvt_pkrtz(p[0], p[1]);
            h2 phi = __builtin_amdgcn_cvt_pkrtz(p[2], p[3]);
            dsum = dot2acc(plo, dsum);
            dsum = dot2acc(phi, dsum);
            h4 pf; pf[0] = plo[0]; pf[1] = plo[1]; pf[2] = phi[0]; pf[3] = phi[1];

            h4 vfrag = *(const h4*)(Vc + t * 256 + lane * 4);
            acc = __builtin_amdgcn_mfma_f32_16x16x16f16(pf, vfrag, acc, 0, 0, 0);
        }
        __syncthreads();
    }

    // denom over this key-group for q=qbase+c, on all lanes of the wave
    dsum += __shfl_xor(dsum, 16);
    dsum += __shfl_xor(dsum, 32);

    // cross-key-group combine through LDS (reuse Kbuf; last barrier done)
    float* ex = (float*)&Kbuf[0][0];
    const int slot = (qt * 64 + lane) * 5;
    if (kg == 1) {
        ex[slot + 0] = acc[0]; ex[slot + 1] = acc[1];
        ex[slot + 2] = acc[2]; ex[slot + 3] = acc[3];
        ex[slot + 4] = dsum;
    }
    __syncthreads();
    if (kg == 0) {
        const float dT = dsum + ex[slot + 4];
        #pragma unroll
        for (int i = 0; i < 4; ++i) {
            const float denom = __shfl(dT, 4 * g + i);
            out[base + (size_t)(qbase + 4 * g + i) * 16 + c] =
                (acc[i] + ex[slot + i]) / denom;
        }
    }
}

// ---------------- round-3 fallback (ws too small) ----------------
#define KROW 20
#define VROW 520

__global__ __launch_bounds__(512, 8) void attn_fwd_v3(
    const float* __restrict__ Qp, const float* __restrict__ Kp,
    const float* __restrict__ Vp, const int* __restrict__ maskp,
    float* __restrict__ out)
{
    __shared__ __align__(16) _Float16 Klds[512 * KROW];
    __shared__ __align__(16) _Float16 Vt[16 * VROW];
    __shared__ __align__(16) float biasf[512];

    const int bid  = blockIdx.x;
    const int bh   = bid >> 5;
    const int qblk = bid & 31;
    const int b    = bh >> 3;
    const int tid  = threadIdx.x;
    const int wave = tid >> 6;
    const int lane = tid & 63;
    const int qt   = wave & 3;
    const int kg   = wave >> 2;
    const int c    = lane & 15;
    const int g    = lane >> 4;

    const size_t base = (size_t)bh * (SEQ * 16);
    const int qbase = qblk * 64 + qt * 16;
    const float c1 = 1.1047809f;
    const float c2 = -28.8539008f;

    h4 qfrag;
    {
        f4 qv = *(const f4*)(Qp + base + (size_t)(qbase + c) * 16 + 4 * g);
        h2 lo = __builtin_amdgcn_cvt_pkrtz(c1 * qv[0], c1 * qv[1]);
        h2 hi = __builtin_amdgcn_cvt_pkrtz(c1 * qv[2], c1 * qv[3]);
        qfrag[0] = lo[0]; qfrag[1] = lo[1]; qfrag[2] = hi[0]; qfrag[3] = hi[1];
    }

    f4 acc = {0.f, 0.f, 0.f, 0.f};
    float dsum = 0.f;
    const int kgb = kg * 256;

    for (int round = 0; round < 4; ++round) {
        {
            const float* Kc = Kp + base + (size_t)round * (512 * 16);
            const float* Vc = Vp + base + (size_t)round * (512 * 16);
            #pragma unroll
            for (int j = 0; j < 4; ++j) {
                const int i = j * 512 + tid;
                f4 kv = *(const f4*)(Kc + (size_t)i * 4);
                f4 vv = *(const f4*)(Vc + (size_t)i * 4);
                const int key = i >> 2;
                const int dq  = (i & 3) * 4;
                h2 k0 = __builtin_amdgcn_cvt_pkrtz(kv[0], kv[1]);
                h2 k1 = __builtin_amdgcn_cvt_pkrtz(kv[2], kv[3]);
                h4 kh; kh[0] = k0[0]; kh[1] = k0[1]; kh[2] = k1[0]; kh[3] = k1[1];
                *(h4*)&Klds[key * KROW + dq] = kh;
                #pragma unroll
                for (int e = 0; e < 4; ++e)
                    Vt[(dq + e) * VROW + key] = (_Float16)vv[e];
            }
            biasf[tid] = maskp[(size_t)b * SEQ + round * 512 + tid] ? -60.0f : 0.0f;
        }
        __syncthreads();

        #pragma unroll
        for (int t = 0; t < 16; ++t) {
            const int kb = kgb + t * 16;
            h4 afrag = *(const h4*)&Klds[(kb + c) * KROW + 4 * g];
            f4 s = __builtin_amdgcn_mfma_f32_16x16x16f16(
                afrag, qfrag, (f4){0.f, 0.f, 0.f, 0.f}, 0, 0, 0);
            f4 b4 = *(const f4*)&biasf[kb + 4 * g];
            float p[4];
            #pragma unroll
            for (int i = 0; i < 4; ++i) {
                float tt = fast_exp2(s[i]);
                float w  = __builtin_amdgcn_rcpf(1.0f + tt);
                p[i] = fast_exp2(__builtin_fmaf(c2, w, b4[i]));
            }
            h2 plo = __builtin_amdgcn_cvt_pkrtz(p[0], p[1]);
            h2 phi = __builtin_amdgcn_cvt_pkrtz(p[2], p[3]);
            dsum = dot2acc(plo, dsum);
            dsum = dot2acc(phi, dsum);
            h4 pf; pf[0] = plo[0]; pf[1] = plo[1]; pf[2] = phi[0]; pf[3] = phi[1];
            h4 vfrag = *(const h4*)&Vt[c * VROW + kb + 4 * g];
            acc = __builtin_amdgcn_mfma_f32_16x16x16f16(pf, vfrag, acc, 0, 0, 0);
        }
        __syncthreads();
    }

    dsum += __shfl_xor(dsum, 16);
    dsum += __shfl_xor(dsum, 32);

    float* ex = (float*)Klds;
    const int slot = (qt * 64 + lane) * 5;
    if (kg == 1) {
        ex[slot + 0] = acc[0]; ex[slot + 1] = acc[1];
        ex[slot + 2] = acc[2]; ex[slot + 3] = acc[3];
        ex[slot + 4] = dsum;
    }
    __syncthreads();
    if (kg == 0) {
        const float dT = dsum + ex[slot + 4];
        #pragma unroll
        for (int i = 0; i < 4; ++i) {
            const float denom = __shfl(dT, 4 * g + i);
            out[base + (size_t)(qbase + 4 * g + i) * 16 + c] =
                (acc[i] + ex[slot + i]) / denom;
        }
    }
}

extern "C" void kernel_launch(void* const* d_in, const int* in_sizes, int n_in,
                              void* d_out, int out_size, void* d_ws, size_t ws_size,
                              hipStream_t stream) {
    const float* Q    = (const float*)d_in[0];
    const float* K    = (const float*)d_in[1];
    const float* V    = (const float*)d_in[2];
    const int*   mask = (const int*)d_in[3];
    float* out = (float*)d_out;

    if (ws_size >= WS_NEEDED) {
        char* p = (char*)d_ws;
        __fp16* Kws = (__fp16*)p;                       p += KWS_BYTES;
        __fp16* Vws = (__fp16*)p;                       p += VWS_BYTES;
        float*  Bws = (float*)p;                        p += BIAS_BYTES;
        int*    Iws = (int*)p;                          p += IDX_BYTES;
        int*    Mws = (int*)p;
        attn_scan<<<dim3(4), dim3(256), 0, stream>>>(mask, Iws, Bws, Mws);
        attn_prep<<<dim3(1024), dim3(256), 0, stream>>>(K, V, Iws, Kws, Vws);
        attn_v5<<<dim3(1024), dim3(512), 0, stream>>>(Q, Kws, Vws, Bws, Mws, out);
    } else {
        attn_fwd_v3<<<dim3(1024), dim3(512), 0, stream>>>(Q, K, V, mask, out);
    }
}